// Round 17
// baseline (64.107 us; speedup 1.0000x reference)
//
#include <hip/hip_runtime.h>
#include <stdint.h>

#define LOG2E 1.4426950408889634f
#define QSCALE_LN2 0.25506068f   // (1/sqrt(32)) * log2(e), folded into Q at projection

typedef __attribute__((ext_vector_type(8))) short bf16x8;
typedef __attribute__((ext_vector_type(4))) float f32x4;

__device__ __forceinline__ unsigned short f2bf(float f) {
  union { float f; unsigned int u; } v; v.f = f;
  unsigned int u = v.u;
  u += 0x7FFFu + ((u >> 16) & 1u);   // round-to-nearest-even
  return (unsigned short)(u >> 16);
}

__device__ __forceinline__ unsigned int cvt_pk_bf16(float lo, float hi) {
  unsigned int r;
  asm("v_cvt_pk_bf16_f32 %0, %1, %2" : "=v"(r) : "v"(lo), "v"(hi));
  return r;
}

// ---------- kernel: transpose 256x256 f32 -> bf16 (weights, k-fast for B-frags) ----------
struct WPtrs { const float* src[4]; unsigned short* dst[4]; };
__global__ void transpose_w(WPtrs p) {
  __shared__ float tile[32][33];
  const float* src = p.src[blockIdx.z];
  unsigned short* dst = p.dst[blockIdx.z];
  int x = blockIdx.x * 32 + threadIdx.x;
  int y = blockIdx.y * 32 + threadIdx.y;
  #pragma unroll
  for (int j = 0; j < 32; j += 8)
    tile[threadIdx.y + j][threadIdx.x] = src[(y + j) * 256 + x];
  __syncthreads();
  int xo = blockIdx.y * 32 + threadIdx.x;
  int yo = blockIdx.x * 32 + threadIdx.y;
  #pragma unroll
  for (int j = 0; j < 32; j += 8)
    dst[(yo + j) * 256 + xo] = f2bf(tile[threadIdx.x][threadIdx.y + j]);
}

// ---------- QKV GEMM (R5-proven): [16384,256] x [256,256], single pass over n ----------
// Q output is pre-scaled by QSCALE_LN2 (softmax scale folded, log2 domain).
__launch_bounds__(256, 3)
__global__ void gemm_qkv(const float* __restrict__ Ax,
                         const unsigned short* __restrict__ Wt,   // [n][k] transposed
                         unsigned short* __restrict__ q_out,
                         unsigned short* __restrict__ k_out,
                         unsigned short* __restrict__ vT) {
  __shared__ unsigned short As[64][72];    // 9 KB
  __shared__ unsigned short Bs[256][72];   // 36 KB
  const int tid = threadIdx.x;
  const int m0 = blockIdx.x * 64;
  const int wsel = blockIdx.y;
  const unsigned short* W = Wt + wsel * 65536;
  const int w = tid >> 6, lane = tid & 63;
  const int n0 = w * 64;
  const int lr = lane & 15, lg = lane >> 4;

  f32x4 acc[4][4] = {};

  for (int kt = 0; kt < 4; ++kt) {
    #pragma unroll
    for (int i = 0; i < 2; ++i) {          // A: 64 rows, f32 -> bf16 during staging
      int c = tid + i * 256;
      int row = c >> 3, colg = c & 7;
      const float* s = &Ax[(size_t)(m0 + row) * 256 + kt * 64 + colg * 8];
      float4 f0 = *reinterpret_cast<const float4*>(s);
      float4 f1 = *reinterpret_cast<const float4*>(s + 4);
      uint4 pk;
      pk.x = cvt_pk_bf16(f0.x, f0.y); pk.y = cvt_pk_bf16(f0.z, f0.w);
      pk.z = cvt_pk_bf16(f1.x, f1.y); pk.w = cvt_pk_bf16(f1.z, f1.w);
      *reinterpret_cast<uint4*>(&As[row][colg * 8]) = pk;
    }
    #pragma unroll
    for (int i = 0; i < 8; ++i) {          // B: 256 rows (full n)
      int c = tid + i * 256;
      int row = c >> 3, colg = c & 7;
      *reinterpret_cast<int4*>(&Bs[row][colg * 8]) =
        *reinterpret_cast<const int4*>(&W[(size_t)row * 256 + kt * 64 + colg * 8]);
    }
    __syncthreads();
    #pragma unroll
    for (int kk = 0; kk < 2; ++kk) {
      bf16x8 af[4], bfr[4];
      #pragma unroll
      for (int mf = 0; mf < 4; ++mf)
        af[mf] = *reinterpret_cast<const bf16x8*>(&As[mf * 16 + lr][kk * 32 + lg * 8]);
      #pragma unroll
      for (int nf = 0; nf < 4; ++nf)
        bfr[nf] = *reinterpret_cast<const bf16x8*>(&Bs[n0 + nf * 16 + lr][kk * 32 + lg * 8]);
      #pragma unroll
      for (int mf = 0; mf < 4; ++mf)
        #pragma unroll
        for (int nf = 0; nf < 4; ++nf)
          acc[mf][nf] = __builtin_amdgcn_mfma_f32_16x16x32_bf16(af[mf], bfr[nf], acc[mf][nf], 0, 0, 0);
    }
    __syncthreads();
  }

  if (wsel < 2) {
    unsigned short* dst = (wsel == 0) ? q_out : k_out;
    const float qs = (wsel == 0) ? QSCALE_LN2 : 1.0f;
    #pragma unroll
    for (int mf = 0; mf < 4; ++mf)
      #pragma unroll
      for (int nf = 0; nf < 4; ++nf)
        #pragma unroll
        for (int r = 0; r < 4; ++r)
          dst[(size_t)(m0 + mf * 16 + lg * 4 + r) * 256 + (n0 + nf * 16 + lr)] =
            f2bf(acc[mf][nf][r] * qs);
  } else {
    #pragma unroll
    for (int mf = 0; mf < 4; ++mf)
      #pragma unroll
      for (int nf = 0; nf < 4; ++nf) {
        int ncol = n0 + nf * 16 + lr;
        int h = ncol >> 5, d = ncol & 31;
        int m = m0 + mf * 16 + lg * 4;
        int b = m >> 9, t = m & 511;
        ushort4 pk;
        pk.x = f2bf(acc[mf][nf][0]); pk.y = f2bf(acc[mf][nf][1]);
        pk.z = f2bf(acc[mf][nf][2]); pk.w = f2bf(acc[mf][nf][3]);
        *reinterpret_cast<ushort4*>(&vT[((size_t)((b * 8 + h) * 32 + d)) * 512 + t]) = pk;
      }
  }
}

// ---------- output GEMM: [16384,256] x [256,128-tile] (proven shape) ----------
__launch_bounds__(256, 3)
__global__ void gemm_out(const unsigned short* __restrict__ Ab,
                         const unsigned short* __restrict__ W,    // wo^T [n][k]
                         const float* __restrict__ bo,
                         float* __restrict__ f_out) {
  __shared__ unsigned short As[128][72];
  __shared__ unsigned short Bs[128][72];
  const int tid = threadIdx.x;
  const int m0 = blockIdx.x * 128;
  const int n0 = blockIdx.y * 128;
  const int w = tid >> 6, lane = tid & 63;
  const int wm = (w >> 1) * 64, wn = (w & 1) * 64;
  const int lr = lane & 15, lg = lane >> 4;

  f32x4 acc[4][4] = {};

  for (int kt = 0; kt < 4; ++kt) {
    #pragma unroll
    for (int cc = 0; cc < 4; ++cc) {
      int c = tid + cc * 256;
      int row = c >> 3, colg = c & 7;
      *reinterpret_cast<int4*>(&As[row][colg * 8]) =
        *reinterpret_cast<const int4*>(&Ab[(size_t)(m0 + row) * 256 + kt * 64 + colg * 8]);
      *reinterpret_cast<int4*>(&Bs[row][colg * 8]) =
        *reinterpret_cast<const int4*>(&W[(size_t)(n0 + row) * 256 + kt * 64 + colg * 8]);
    }
    __syncthreads();
    #pragma unroll
    for (int kk = 0; kk < 2; ++kk) {
      bf16x8 af[4], bfr[4];
      #pragma unroll
      for (int mf = 0; mf < 4; ++mf)
        af[mf] = *reinterpret_cast<const bf16x8*>(&As[wm + mf * 16 + lr][kk * 32 + lg * 8]);
      #pragma unroll
      for (int nf = 0; nf < 4; ++nf)
        bfr[nf] = *reinterpret_cast<const bf16x8*>(&Bs[wn + nf * 16 + lr][kk * 32 + lg * 8]);
      #pragma unroll
      for (int mf = 0; mf < 4; ++mf)
        #pragma unroll
        for (int nf = 0; nf < 4; ++nf)
          acc[mf][nf] = __builtin_amdgcn_mfma_f32_16x16x32_bf16(af[mf], bfr[nf], acc[mf][nf], 0, 0, 0);
    }
    __syncthreads();
  }

  #pragma unroll
  for (int mf = 0; mf < 4; ++mf)
    #pragma unroll
    for (int nf = 0; nf < 4; ++nf)
      #pragma unroll
      for (int r = 0; r < 4; ++r) {
        int ncol = n0 + wn + nf * 16 + lr;
        f_out[(size_t)(m0 + wm + mf * 16 + lg * 4 + r) * 256 + ncol] = acc[mf][nf][r] + bo[ncol];
      }
}

// ---------- fused causal attention: ONE block per (b,h), 16 waves (4/SIMD TLP) ----------
// grid (8, 32) = 256 blocks, 1024 threads, 128 KB static LDS, 1 block/CU.
// K/V staged once; wave g in 0..15 runs chunk pair (g, 31-g) = 9 steps each
// (perfectly balanced). vf loaded per-ks inside PV (keeps VGPR <= 128 for the
// forced 4-waves/SIMD residency); kf hoisted (shared by both chains).
struct CSt {
  bf16x8 qf;
  f32x4 o0, o1;
  float m, l, bb0;
  int nfull, qq;
};

__device__ __forceinline__ void attn_init(CSt& st, int c, const unsigned short* qb,
    int b, int h, int lr, int lg, float slope2) {
  st.qq = c * 16;
  st.qf = *reinterpret_cast<const bf16x8*>(
      &qb[(size_t)(b * 512 + st.qq + lr) * 256 + h * 32 + lg * 8]);
  f32x4 z = {0.f, 0.f, 0.f, 0.f};
  st.o0 = z; st.o1 = z;
  st.m = -1e30f; st.l = 0.f;
  st.nfull = (st.qq >= 63) ? ((st.qq - 63) / 64 + 1) : 0;
  st.bb0 = slope2 * (float)(lg * 4 - lr - st.qq);
}

// single-step (R12-proven; vf loaded per-ks from LDS)
__device__ __forceinline__ void attn_step(CSt& st, int s,
    const bf16x8* kf, const unsigned short* __restrict__ Vs, char* __restrict__ Pw,
    int lr, int lg, float slope2, const float* cc, int swz) {
  const int kb0 = s * 64;
  f32x4 sv[4];
  __builtin_amdgcn_s_setprio(1);
  #pragma unroll
  for (int t = 0; t < 4; ++t) {
    f32x4 z = {0.f, 0.f, 0.f, 0.f};
    sv[t] = __builtin_amdgcn_mfma_f32_16x16x32_bf16(kf[t], st.qf, z, 0, 0, 0);
  }
  __builtin_amdgcn_s_setprio(0);
  float bb = st.bb0 + slope2 * (float)kb0;
  float x[16];
  #pragma unroll
  for (int t = 0; t < 4; ++t)
    #pragma unroll
    for (int r = 0; r < 4; ++r)
      x[t * 4 + r] = sv[t][r] + (bb + cc[t * 4 + r]);
  if (s >= st.nfull) {                                // boundary step: causal mask
    int thr = st.qq + lr - kb0 - lg * 4;
    #pragma unroll
    for (int t = 0; t < 4; ++t)
      #pragma unroll
      for (int r = 0; r < 4; ++r)
        x[t * 4 + r] = ((t * 16 + r) <= thr) ? x[t * 4 + r] : -1e30f;
  }
  float bm = x[0];
  #pragma unroll
  for (int j = 1; j < 16; ++j) bm = fmaxf(bm, x[j]);
  bm = fmaxf(bm, __shfl_xor(bm, 16));
  bm = fmaxf(bm, __shfl_xor(bm, 32));
  float mn = fmaxf(st.m, bm);
  float alpha = __builtin_amdgcn_exp2f(st.m - mn);
  st.m = mn;
  st.l *= alpha;
  #pragma unroll
  for (int r = 0; r < 4; ++r) { st.o0[r] *= alpha; st.o1[r] *= alpha; }
  float ps = 0.f;
  #pragma unroll
  for (int j = 0; j < 16; ++j) { x[j] = __builtin_amdgcn_exp2f(x[j] - mn); ps += x[j]; }
  st.l += ps;
  char* Prow = Pw + lr * 256;                          // 256 B rows; use first 128 B
  #pragma unroll
  for (int t = 0; t < 4; ++t)
    #pragma unroll
    for (int pp = 0; pp < 2; ++pp) {
      unsigned int w2 = cvt_pk_bf16(x[t * 4 + 2 * pp], x[t * 4 + 2 * pp + 1]);
      *reinterpret_cast<unsigned int*>(Prow + ((t * 32 + lg * 8 + pp * 4) ^ swz)) = w2;
    }
  __builtin_amdgcn_s_setprio(1);
  #pragma unroll
  for (int ks = 0; ks < 2; ++ks) {
    bf16x8 pb = *reinterpret_cast<const bf16x8*>(Prow + ((ks * 64 + lg * 16) ^ swz));
    #pragma unroll
    for (int dt = 0; dt < 2; ++dt) {
      int d = dt * 16 + lr;
      int col = (kb0 + ks * 32 + lg * 8) ^ ((d & 7) << 3);
      bf16x8 vfr = *reinterpret_cast<const bf16x8*>(&Vs[d * 512 + col]);
      if (dt == 0) st.o0 = __builtin_amdgcn_mfma_f32_16x16x32_bf16(vfr, pb, st.o0, 0, 0, 0);
      else         st.o1 = __builtin_amdgcn_mfma_f32_16x16x32_bf16(vfr, pb, st.o1, 0, 0, 0);
    }
  }
  __builtin_amdgcn_s_setprio(0);
}

// double-step: tiles s and s+1 (128 keys), one online-softmax update.
__device__ __forceinline__ void attn_step2(CSt& st, int s, bool maskB,
    const bf16x8* kf, const unsigned short* __restrict__ Vs, char* __restrict__ Pw,
    int lr, int lg, float slope2, const float* cc, int swz) {
  const int kb0 = s * 64;
  f32x4 sv[8];
  __builtin_amdgcn_s_setprio(1);
  #pragma unroll
  for (int t = 0; t < 8; ++t) {
    f32x4 z = {0.f, 0.f, 0.f, 0.f};
    sv[t] = __builtin_amdgcn_mfma_f32_16x16x32_bf16(kf[t], st.qf, z, 0, 0, 0);
  }
  __builtin_amdgcn_s_setprio(0);
  const float bbA = st.bb0 + slope2 * (float)kb0;
  const float bbB = bbA + slope2 * 64.0f;
  float x[32];
  #pragma unroll
  for (int t = 0; t < 4; ++t)
    #pragma unroll
    for (int r = 0; r < 4; ++r) {
      x[t * 4 + r]      = sv[t][r]     + (bbA + cc[t * 4 + r]);
      x[16 + t * 4 + r] = sv[4 + t][r] + (bbB + cc[t * 4 + r]);
    }
  if (maskB) {
    int thr = st.qq + lr - (kb0 + 64) - lg * 4;
    #pragma unroll
    for (int t = 0; t < 4; ++t)
      #pragma unroll
      for (int r = 0; r < 4; ++r)
        x[16 + t * 4 + r] = ((t * 16 + r) <= thr) ? x[16 + t * 4 + r] : -1e30f;
  }
  float bm = x[0];
  #pragma unroll
  for (int j = 1; j < 32; ++j) bm = fmaxf(bm, x[j]);
  bm = fmaxf(bm, __shfl_xor(bm, 16));
  bm = fmaxf(bm, __shfl_xor(bm, 32));
  float mn = fmaxf(st.m, bm);
  float alpha = __builtin_amdgcn_exp2f(st.m - mn);
  st.m = mn;
  st.l *= alpha;
  #pragma unroll
  for (int r = 0; r < 4; ++r) { st.o0[r] *= alpha; st.o1[r] *= alpha; }
  float ps = 0.f;
  #pragma unroll
  for (int j = 0; j < 32; ++j) { x[j] = __builtin_amdgcn_exp2f(x[j] - mn); ps += x[j]; }
  st.l += ps;
  char* Prow = Pw + lr * 256;                          // [0,128): tile A, [128,256): tile B
  #pragma unroll
  for (int t = 0; t < 4; ++t)
    #pragma unroll
    for (int pp = 0; pp < 2; ++pp) {
      const int cb = (t * 32 + lg * 8 + pp * 4) ^ swz;
      *reinterpret_cast<unsigned int*>(Prow + cb) =
          cvt_pk_bf16(x[t * 4 + 2 * pp], x[t * 4 + 2 * pp + 1]);
      *reinterpret_cast<unsigned int*>(Prow + 128 + cb) =
          cvt_pk_bf16(x[16 + t * 4 + 2 * pp], x[16 + t * 4 + 2 * pp + 1]);
    }
  __builtin_amdgcn_s_setprio(1);
  #pragma unroll
  for (int ks = 0; ks < 4; ++ks) {
    const int cb = (ks >> 1) * 128 + ((((ks & 1) * 64) + lg * 16) ^ swz);
    bf16x8 pb = *reinterpret_cast<const bf16x8*>(Prow + cb);
    #pragma unroll
    for (int dt = 0; dt < 2; ++dt) {
      int d = dt * 16 + lr;
      int col = (kb0 + ks * 32 + lg * 8) ^ ((d & 7) << 3);
      bf16x8 vfr = *reinterpret_cast<const bf16x8*>(&Vs[d * 512 + col]);
      if (dt == 0) st.o0 = __builtin_amdgcn_mfma_f32_16x16x32_bf16(vfr, pb, st.o0, 0, 0, 0);
      else         st.o1 = __builtin_amdgcn_mfma_f32_16x16x32_bf16(vfr, pb, st.o1, 0, 0, 0);
    }
  }
  __builtin_amdgcn_s_setprio(0);
}

__device__ __forceinline__ void attn_fin(CSt& st, unsigned short* __restrict__ ob,
                                         int b, int h, int lr, int lg) {
  float l = st.l;
  l += __shfl_xor(l, 16);
  l += __shfl_xor(l, 32);
  float inv = 1.0f / l;
  unsigned int w0 = cvt_pk_bf16(st.o0[0] * inv, st.o0[1] * inv);
  unsigned int w1 = cvt_pk_bf16(st.o0[2] * inv, st.o0[3] * inv);
  unsigned int w2 = cvt_pk_bf16(st.o1[0] * inv, st.o1[1] * inv);
  unsigned int w3 = cvt_pk_bf16(st.o1[2] * inv, st.o1[3] * inv);
  size_t obase = (size_t)(b * 512 + st.qq + lr) * 256 + h * 32;
  *reinterpret_cast<uint2*>(&ob[obase + lg * 4]) = make_uint2(w0, w1);
  *reinterpret_cast<uint2*>(&ob[obase + 16 + lg * 4]) = make_uint2(w2, w3);
}

// dispatch one chunk's work for the tile-pair starting at s
__device__ __forceinline__ void chunk_phase(CSt& st, int s, int nc,
    const bf16x8* kf, const unsigned short* __restrict__ Vs, char* Pw,
    int lr, int lg, float slope2, const float* cc, int swz) {
  if (s >= nc) return;
  if (s + 1 < nc)
    attn_step2(st, s, (s + 2 >= nc), kf, Vs, Pw, lr, lg, slope2, cc, swz);
  else
    attn_step(st, s, kf, Vs, Pw, lr, lg, slope2, cc, swz);   // odd tail, self-masks
}

__launch_bounds__(1024)
__global__ void attn_k(const unsigned short* __restrict__ qb,
                       const unsigned short* __restrict__ kb,
                       const unsigned short* __restrict__ vT,
                       unsigned short* __restrict__ ob) {
  __shared__ unsigned short Ks[512 * 32];   // chunk-swizzled, 32 KB
  __shared__ unsigned short Vs[32 * 512];   // col-swizzled, 32 KB
  __shared__ char Pb[65536];                // 16 waves x 4 KB strips
  const int h = blockIdx.x, b = blockIdx.y;
  const int tid = threadIdx.x, wv = tid >> 6, lane = tid & 63;
  const int lr = lane & 15, lg = lane >> 4;

  // ---- stage K rows [t][d] (chunk-swizzled) and V^T rows [d][t] (swizzled), 1024 threads ----
  {
    const unsigned short* ksrc = kb + ((size_t)b * 512) * 256 + h * 32;
    #pragma unroll
    for (int it = 0; it < 2; ++it) {
      int idx = tid + it * 1024;
      int row = idx >> 2, g = idx & 3;
      int gs = g ^ ((row >> 1) & 3);
      *reinterpret_cast<int4*>(&Ks[row * 32 + gs * 8]) =
        *reinterpret_cast<const int4*>(&ksrc[(size_t)row * 256 + g * 8]);
    }
    const unsigned short* vsrc = vT + ((size_t)(b * 8 + h) * 32) * 512;
    #pragma unroll
    for (int it = 0; it < 2; ++it) {
      int idx = tid + it * 1024;
      int d = idx >> 6, cg = idx & 63;
      int col = (cg * 8) ^ ((d & 7) << 3);
      *reinterpret_cast<int4*>(&Vs[d * 512 + col]) =
        *reinterpret_cast<const int4*>(&vsrc[(size_t)d * 512 + cg * 8]);
    }
  }
  __syncthreads();

  const float slope2 = exp2f(-(float)(h + 1)) * LOG2E; // ALiBi slope, log2 domain
  float cc[16];
  #pragma unroll
  for (int t = 0; t < 4; ++t)
    #pragma unroll
    for (int r = 0; r < 4; ++r) cc[t * 4 + r] = slope2 * (float)(t * 16 + r);
  const int swz = (lr & 7) << 4;
  const int kchunk = (lg ^ ((lr >> 1) & 3)) * 8;       // Ks swizzled chunk position
  char* Pw = Pb + wv * 4096;

  const int g = wv;                                    // wave id 0..15
  const int cA = g, cB = 31 - g;
  CSt A, B;
  attn_init(A, cA, qb, b, h, lr, lg, slope2);
  attn_init(B, cB, qb, b, h, lr, lg, slope2);
  const int nA = cA / 4 + 1, nB = cB / 4 + 1;          // nA + nB = 9 always

  for (int s = 0; s < nB; s += 2) {
    const int kb0 = s * 64;
    bf16x8 kf[8];                                      // tiles s and s+1 (rows < 512 always)
    #pragma unroll
    for (int t = 0; t < 8; ++t)
      kf[t] = *reinterpret_cast<const bf16x8*>(&Ks[(kb0 + t * 16 + lr) * 32 + kchunk]);
    chunk_phase(A, s, nA, kf, Vs, Pw, lr, lg, slope2, cc, swz);
    chunk_phase(B, s, nB, kf, Vs, Pw, lr, lg, slope2, cc, swz);
  }

  attn_fin(A, ob, b, h, lr, lg);
  attn_fin(B, ob, b, h, lr, lg);
}

extern "C" void kernel_launch(void* const* d_in, const int* in_sizes, int n_in,
                              void* d_out, int out_size, void* d_ws, size_t ws_size,
                              hipStream_t stream) {
  const float* x  = (const float*)d_in[0];
  const float* Wq = (const float*)d_in[1];
  const float* Wk = (const float*)d_in[2];
  const float* Wv = (const float*)d_in[3];
  const float* Wo = (const float*)d_in[4];
  const float* bo = (const float*)d_in[5];
  float* out = (float*)d_out;

  char* ws = (char*)d_ws;
  unsigned short* qb = (unsigned short*)(ws);                    // 8 MB
  unsigned short* kb = (unsigned short*)(ws + (8u  << 20));      // 8 MB
  unsigned short* vT = (unsigned short*)(ws + (16u << 20));      // 8 MB
  unsigned short* ob = (unsigned short*)(ws + (24u << 20));      // 8 MB
  unsigned short* wt = (unsigned short*)(ws + (32u << 20));      // 4 x 128 KB transposed weights

  WPtrs p;
  p.src[0] = Wq; p.src[1] = Wk; p.src[2] = Wv; p.src[3] = Wo;
  p.dst[0] = wt; p.dst[1] = wt + 65536; p.dst[2] = wt + 2 * 65536; p.dst[3] = wt + 3 * 65536;
  transpose_w<<<dim3(8, 8, 4), dim3(32, 8), 0, stream>>>(p);

  gemm_qkv<<<dim3(256, 3), 256, 0, stream>>>(x, wt, qb, kb, vT);
  attn_k<<<dim3(8, 32), 1024, 0, stream>>>(qb, kb, vT, ob);
  gemm_out<<<dim3(128, 2), 256, 0, stream>>>(ob, wt + 3 * 65536, bo, out);
}

// Round 18
// 53.755 us; speedup vs baseline: 1.1926x; 1.1926x over previous
//
#include <hip/hip_runtime.h>
#include <stdint.h>

#define LOG2E 1.4426950408889634f
#define QSCALE_LN2 0.25506068f   // (1/sqrt(32)) * log2(e), folded into Q at projection

typedef __attribute__((ext_vector_type(8))) short bf16x8;
typedef __attribute__((ext_vector_type(4))) float f32x4;

__device__ __forceinline__ unsigned short f2bf(float f) {
  union { float f; unsigned int u; } v; v.f = f;
  unsigned int u = v.u;
  u += 0x7FFFu + ((u >> 16) & 1u);   // round-to-nearest-even
  return (unsigned short)(u >> 16);
}

__device__ __forceinline__ unsigned int cvt_pk_bf16(float lo, float hi) {
  unsigned int r;
  asm("v_cvt_pk_bf16_f32 %0, %1, %2" : "=v"(r) : "v"(lo), "v"(hi));
  return r;
}

// ---------- kernel: transpose 256x256 f32 -> bf16 (weights, k-fast for B-frags) ----------
struct WPtrs { const float* src[4]; unsigned short* dst[4]; };
__global__ void transpose_w(WPtrs p) {
  __shared__ float tile[32][33];
  const float* src = p.src[blockIdx.z];
  unsigned short* dst = p.dst[blockIdx.z];
  int x = blockIdx.x * 32 + threadIdx.x;
  int y = blockIdx.y * 32 + threadIdx.y;
  #pragma unroll
  for (int j = 0; j < 32; j += 8)
    tile[threadIdx.y + j][threadIdx.x] = src[(y + j) * 256 + x];
  __syncthreads();
  int xo = blockIdx.y * 32 + threadIdx.x;
  int yo = blockIdx.x * 32 + threadIdx.y;
  #pragma unroll
  for (int j = 0; j < 32; j += 8)
    dst[(yo + j) * 256 + xo] = f2bf(tile[threadIdx.x][threadIdx.y + j]);
}

// ---------- QKV GEMM (R5-proven): [16384,256] x [256,256], single pass over n ----------
// Q output is pre-scaled by QSCALE_LN2 (softmax scale folded, log2 domain).
__launch_bounds__(256, 3)
__global__ void gemm_qkv(const float* __restrict__ Ax,
                         const unsigned short* __restrict__ Wt,   // [n][k] transposed
                         unsigned short* __restrict__ q_out,
                         unsigned short* __restrict__ k_out,
                         unsigned short* __restrict__ vT) {
  __shared__ unsigned short As[64][72];    // 9 KB
  __shared__ unsigned short Bs[256][72];   // 36 KB
  const int tid = threadIdx.x;
  const int m0 = blockIdx.x * 64;
  const int wsel = blockIdx.y;
  const unsigned short* W = Wt + wsel * 65536;
  const int w = tid >> 6, lane = tid & 63;
  const int n0 = w * 64;
  const int lr = lane & 15, lg = lane >> 4;

  f32x4 acc[4][4] = {};

  for (int kt = 0; kt < 4; ++kt) {
    #pragma unroll
    for (int i = 0; i < 2; ++i) {          // A: 64 rows, f32 -> bf16 during staging
      int c = tid + i * 256;
      int row = c >> 3, colg = c & 7;
      const float* s = &Ax[(size_t)(m0 + row) * 256 + kt * 64 + colg * 8];
      float4 f0 = *reinterpret_cast<const float4*>(s);
      float4 f1 = *reinterpret_cast<const float4*>(s + 4);
      uint4 pk;
      pk.x = cvt_pk_bf16(f0.x, f0.y); pk.y = cvt_pk_bf16(f0.z, f0.w);
      pk.z = cvt_pk_bf16(f1.x, f1.y); pk.w = cvt_pk_bf16(f1.z, f1.w);
      *reinterpret_cast<uint4*>(&As[row][colg * 8]) = pk;
    }
    #pragma unroll
    for (int i = 0; i < 8; ++i) {          // B: 256 rows (full n)
      int c = tid + i * 256;
      int row = c >> 3, colg = c & 7;
      *reinterpret_cast<int4*>(&Bs[row][colg * 8]) =
        *reinterpret_cast<const int4*>(&W[(size_t)row * 256 + kt * 64 + colg * 8]);
    }
    __syncthreads();
    #pragma unroll
    for (int kk = 0; kk < 2; ++kk) {
      bf16x8 af[4], bfr[4];
      #pragma unroll
      for (int mf = 0; mf < 4; ++mf)
        af[mf] = *reinterpret_cast<const bf16x8*>(&As[mf * 16 + lr][kk * 32 + lg * 8]);
      #pragma unroll
      for (int nf = 0; nf < 4; ++nf)
        bfr[nf] = *reinterpret_cast<const bf16x8*>(&Bs[n0 + nf * 16 + lr][kk * 32 + lg * 8]);
      #pragma unroll
      for (int mf = 0; mf < 4; ++mf)
        #pragma unroll
        for (int nf = 0; nf < 4; ++nf)
          acc[mf][nf] = __builtin_amdgcn_mfma_f32_16x16x32_bf16(af[mf], bfr[nf], acc[mf][nf], 0, 0, 0);
    }
    __syncthreads();
  }

  if (wsel < 2) {
    unsigned short* dst = (wsel == 0) ? q_out : k_out;
    const float qs = (wsel == 0) ? QSCALE_LN2 : 1.0f;
    #pragma unroll
    for (int mf = 0; mf < 4; ++mf)
      #pragma unroll
      for (int nf = 0; nf < 4; ++nf)
        #pragma unroll
        for (int r = 0; r < 4; ++r)
          dst[(size_t)(m0 + mf * 16 + lg * 4 + r) * 256 + (n0 + nf * 16 + lr)] =
            f2bf(acc[mf][nf][r] * qs);
  } else {
    #pragma unroll
    for (int mf = 0; mf < 4; ++mf)
      #pragma unroll
      for (int nf = 0; nf < 4; ++nf) {
        int ncol = n0 + nf * 16 + lr;
        int h = ncol >> 5, d = ncol & 31;
        int m = m0 + mf * 16 + lg * 4;
        int b = m >> 9, t = m & 511;
        ushort4 pk;
        pk.x = f2bf(acc[mf][nf][0]); pk.y = f2bf(acc[mf][nf][1]);
        pk.z = f2bf(acc[mf][nf][2]); pk.w = f2bf(acc[mf][nf][3]);
        *reinterpret_cast<ushort4*>(&vT[((size_t)((b * 8 + h) * 32 + d)) * 512 + t]) = pk;
      }
  }
}

// ---------- output GEMM: [16384,256] x [256,128-tile] (proven shape) ----------
__launch_bounds__(256, 3)
__global__ void gemm_out(const unsigned short* __restrict__ Ab,
                         const unsigned short* __restrict__ W,    // wo^T [n][k]
                         const float* __restrict__ bo,
                         float* __restrict__ f_out) {
  __shared__ unsigned short As[128][72];
  __shared__ unsigned short Bs[128][72];
  const int tid = threadIdx.x;
  const int m0 = blockIdx.x * 128;
  const int n0 = blockIdx.y * 128;
  const int w = tid >> 6, lane = tid & 63;
  const int wm = (w >> 1) * 64, wn = (w & 1) * 64;
  const int lr = lane & 15, lg = lane >> 4;

  f32x4 acc[4][4] = {};

  for (int kt = 0; kt < 4; ++kt) {
    #pragma unroll
    for (int cc = 0; cc < 4; ++cc) {
      int c = tid + cc * 256;
      int row = c >> 3, colg = c & 7;
      *reinterpret_cast<int4*>(&As[row][colg * 8]) =
        *reinterpret_cast<const int4*>(&Ab[(size_t)(m0 + row) * 256 + kt * 64 + colg * 8]);
      *reinterpret_cast<int4*>(&Bs[row][colg * 8]) =
        *reinterpret_cast<const int4*>(&W[(size_t)(n0 + row) * 256 + kt * 64 + colg * 8]);
    }
    __syncthreads();
    #pragma unroll
    for (int kk = 0; kk < 2; ++kk) {
      bf16x8 af[4], bfr[4];
      #pragma unroll
      for (int mf = 0; mf < 4; ++mf)
        af[mf] = *reinterpret_cast<const bf16x8*>(&As[wm + mf * 16 + lr][kk * 32 + lg * 8]);
      #pragma unroll
      for (int nf = 0; nf < 4; ++nf)
        bfr[nf] = *reinterpret_cast<const bf16x8*>(&Bs[wn + nf * 16 + lr][kk * 32 + lg * 8]);
      #pragma unroll
      for (int mf = 0; mf < 4; ++mf)
        #pragma unroll
        for (int nf = 0; nf < 4; ++nf)
          acc[mf][nf] = __builtin_amdgcn_mfma_f32_16x16x32_bf16(af[mf], bfr[nf], acc[mf][nf], 0, 0, 0);
    }
    __syncthreads();
  }

  #pragma unroll
  for (int mf = 0; mf < 4; ++mf)
    #pragma unroll
    for (int nf = 0; nf < 4; ++nf)
      #pragma unroll
      for (int r = 0; r < 4; ++r) {
        int ncol = n0 + wn + nf * 16 + lr;
        f_out[(size_t)(m0 + wm + mf * 16 + lg * 4 + r) * 256 + ncol] = acc[mf][nf][r] + bo[ncol];
      }
}

// ---------- fused causal attention with ALiBi: ONE block per (b,h), 8 waves ----------
// grid (8, 32) = 256 blocks, 512 threads, 96 KB static LDS (1 block/CU).
// K/V staged ONCE per (b,h). Wave g = wv in 0..7 runs the R12 chunk set
// {g, 15-g, 16+g, 31-g} with byte-identical step code.
struct CSt {
  bf16x8 qf;
  f32x4 o0, o1;
  float m, l, bb0;
  int nfull, qq;
};

__device__ __forceinline__ void attn_init(CSt& st, int c, const unsigned short* qb,
    int b, int h, int lr, int lg, float slope2) {
  st.qq = c * 16;
  st.qf = *reinterpret_cast<const bf16x8*>(
      &qb[(size_t)(b * 512 + st.qq + lr) * 256 + h * 32 + lg * 8]);
  f32x4 z = {0.f, 0.f, 0.f, 0.f};
  st.o0 = z; st.o1 = z;
  st.m = -1e30f; st.l = 0.f;
  st.nfull = (st.qq >= 63) ? ((st.qq - 63) / 64 + 1) : 0;
  st.bb0 = slope2 * (float)(lg * 4 - lr - st.qq);
}

// single-step (R12-proven)
__device__ __forceinline__ void attn_step(CSt& st, int s,
    const bf16x8* kf, const bf16x8* vf, char* __restrict__ Pw,
    int lr, int lg, float slope2, const float* cc, int swz) {
  const int kb0 = s * 64;
  f32x4 sv[4];
  __builtin_amdgcn_s_setprio(1);
  #pragma unroll
  for (int t = 0; t < 4; ++t) {
    f32x4 z = {0.f, 0.f, 0.f, 0.f};
    sv[t] = __builtin_amdgcn_mfma_f32_16x16x32_bf16(kf[t], st.qf, z, 0, 0, 0);
  }
  __builtin_amdgcn_s_setprio(0);
  float bb = st.bb0 + slope2 * (float)kb0;
  float x[16];
  #pragma unroll
  for (int t = 0; t < 4; ++t)
    #pragma unroll
    for (int r = 0; r < 4; ++r)
      x[t * 4 + r] = sv[t][r] + (bb + cc[t * 4 + r]);
  if (s >= st.nfull) {                                // boundary step: causal mask
    int thr = st.qq + lr - kb0 - lg * 4;
    #pragma unroll
    for (int t = 0; t < 4; ++t)
      #pragma unroll
      for (int r = 0; r < 4; ++r)
        x[t * 4 + r] = ((t * 16 + r) <= thr) ? x[t * 4 + r] : -1e30f;
  }
  float bm = x[0];
  #pragma unroll
  for (int j = 1; j < 16; ++j) bm = fmaxf(bm, x[j]);
  bm = fmaxf(bm, __shfl_xor(bm, 16));
  bm = fmaxf(bm, __shfl_xor(bm, 32));
  float mn = fmaxf(st.m, bm);
  float alpha = __builtin_amdgcn_exp2f(st.m - mn);
  st.m = mn;
  st.l *= alpha;
  #pragma unroll
  for (int r = 0; r < 4; ++r) { st.o0[r] *= alpha; st.o1[r] *= alpha; }
  float ps = 0.f;
  #pragma unroll
  for (int j = 0; j < 16; ++j) { x[j] = __builtin_amdgcn_exp2f(x[j] - mn); ps += x[j]; }
  st.l += ps;
  char* Prow = Pw + lr * 256;                          // 256 B rows; use first 128 B
  #pragma unroll
  for (int t = 0; t < 4; ++t)
    #pragma unroll
    for (int pp = 0; pp < 2; ++pp) {
      unsigned int w2 = cvt_pk_bf16(x[t * 4 + 2 * pp], x[t * 4 + 2 * pp + 1]);
      *reinterpret_cast<unsigned int*>(Prow + ((t * 32 + lg * 8 + pp * 4) ^ swz)) = w2;
    }
  __builtin_amdgcn_s_setprio(1);
  #pragma unroll
  for (int ks = 0; ks < 2; ++ks) {
    bf16x8 pb = *reinterpret_cast<const bf16x8*>(Prow + ((ks * 64 + lg * 16) ^ swz));
    st.o0 = __builtin_amdgcn_mfma_f32_16x16x32_bf16(vf[ks * 2 + 0], pb, st.o0, 0, 0, 0);
    st.o1 = __builtin_amdgcn_mfma_f32_16x16x32_bf16(vf[ks * 2 + 1], pb, st.o1, 0, 0, 0);
  }
  __builtin_amdgcn_s_setprio(0);
}

// double-step: tiles s and s+1 (128 keys), one online-softmax update.
__device__ __forceinline__ void attn_step2(CSt& st, int s, bool maskB,
    const bf16x8* kf, const bf16x8* vf, char* __restrict__ Pw,
    int lr, int lg, float slope2, const float* cc, int swz) {
  const int kb0 = s * 64;
  f32x4 sv[8];
  __builtin_amdgcn_s_setprio(1);
  #pragma unroll
  for (int t = 0; t < 8; ++t) {
    f32x4 z = {0.f, 0.f, 0.f, 0.f};
    sv[t] = __builtin_amdgcn_mfma_f32_16x16x32_bf16(kf[t], st.qf, z, 0, 0, 0);
  }
  __builtin_amdgcn_s_setprio(0);
  const float bbA = st.bb0 + slope2 * (float)kb0;
  const float bbB = bbA + slope2 * 64.0f;
  float x[32];
  #pragma unroll
  for (int t = 0; t < 4; ++t)
    #pragma unroll
    for (int r = 0; r < 4; ++r) {
      x[t * 4 + r]      = sv[t][r]     + (bbA + cc[t * 4 + r]);
      x[16 + t * 4 + r] = sv[4 + t][r] + (bbB + cc[t * 4 + r]);
    }
  if (maskB) {
    int thr = st.qq + lr - (kb0 + 64) - lg * 4;
    #pragma unroll
    for (int t = 0; t < 4; ++t)
      #pragma unroll
      for (int r = 0; r < 4; ++r)
        x[16 + t * 4 + r] = ((t * 16 + r) <= thr) ? x[16 + t * 4 + r] : -1e30f;
  }
  float bm = x[0];
  #pragma unroll
  for (int j = 1; j < 32; ++j) bm = fmaxf(bm, x[j]);
  bm = fmaxf(bm, __shfl_xor(bm, 16));
  bm = fmaxf(bm, __shfl_xor(bm, 32));
  float mn = fmaxf(st.m, bm);
  float alpha = __builtin_amdgcn_exp2f(st.m - mn);
  st.m = mn;
  st.l *= alpha;
  #pragma unroll
  for (int r = 0; r < 4; ++r) { st.o0[r] *= alpha; st.o1[r] *= alpha; }
  float ps = 0.f;
  #pragma unroll
  for (int j = 0; j < 32; ++j) { x[j] = __builtin_amdgcn_exp2f(x[j] - mn); ps += x[j]; }
  st.l += ps;
  char* Prow = Pw + lr * 256;                          // [0,128): tile A, [128,256): tile B
  #pragma unroll
  for (int t = 0; t < 4; ++t)
    #pragma unroll
    for (int pp = 0; pp < 2; ++pp) {
      const int cb = (t * 32 + lg * 8 + pp * 4) ^ swz;
      *reinterpret_cast<unsigned int*>(Prow + cb) =
          cvt_pk_bf16(x[t * 4 + 2 * pp], x[t * 4 + 2 * pp + 1]);
      *reinterpret_cast<unsigned int*>(Prow + 128 + cb) =
          cvt_pk_bf16(x[16 + t * 4 + 2 * pp], x[16 + t * 4 + 2 * pp + 1]);
    }
  __builtin_amdgcn_s_setprio(1);
  #pragma unroll
  for (int ks = 0; ks < 4; ++ks) {
    const int cb = (ks >> 1) * 128 + ((((ks & 1) * 64) + lg * 16) ^ swz);
    bf16x8 pb = *reinterpret_cast<const bf16x8*>(Prow + cb);
    st.o0 = __builtin_amdgcn_mfma_f32_16x16x32_bf16(vf[ks * 2 + 0], pb, st.o0, 0, 0, 0);
    st.o1 = __builtin_amdgcn_mfma_f32_16x16x32_bf16(vf[ks * 2 + 1], pb, st.o1, 0, 0, 0);
  }
  __builtin_amdgcn_s_setprio(0);
}

__device__ __forceinline__ void attn_fin(CSt& st, unsigned short* __restrict__ ob,
                                         int b, int h, int lr, int lg) {
  float l = st.l;
  l += __shfl_xor(l, 16);
  l += __shfl_xor(l, 32);
  float inv = 1.0f / l;
  unsigned int w0 = cvt_pk_bf16(st.o0[0] * inv, st.o0[1] * inv);
  unsigned int w1 = cvt_pk_bf16(st.o0[2] * inv, st.o0[3] * inv);
  unsigned int w2 = cvt_pk_bf16(st.o1[0] * inv, st.o1[1] * inv);
  unsigned int w3 = cvt_pk_bf16(st.o1[2] * inv, st.o1[3] * inv);
  size_t obase = (size_t)(b * 512 + st.qq + lr) * 256 + h * 32;
  *reinterpret_cast<uint2*>(&ob[obase + lg * 4]) = make_uint2(w0, w1);
  *reinterpret_cast<uint2*>(&ob[obase + 16 + lg * 4]) = make_uint2(w2, w3);
}

// dispatch one chunk's work for the tile-pair starting at s
__device__ __forceinline__ void chunk_phase(CSt& st, int s, int nc,
    const bf16x8* kf, const bf16x8* vf, char* Pw,
    int lr, int lg, float slope2, const float* cc, int swz) {
  if (s >= nc) return;
  if (s + 1 < nc)
    attn_step2(st, s, (s + 2 >= nc), kf, vf, Pw, lr, lg, slope2, cc, swz);
  else
    attn_step(st, s, kf, vf, Pw, lr, lg, slope2, cc, swz);   // odd tail, self-masks
}

__launch_bounds__(512)
__global__ void attn_k(const unsigned short* __restrict__ qb,
                       const unsigned short* __restrict__ kb,
                       const unsigned short* __restrict__ vT,
                       unsigned short* __restrict__ ob) {
  __shared__ unsigned short Ks[512 * 32];   // chunk-swizzled, 32 KB
  __shared__ unsigned short Vs[32 * 512];   // col-swizzled, 32 KB
  __shared__ char Pb[32768];                // 8 waves x 4 KB strips
  const int h = blockIdx.x, b = blockIdx.y;
  const int tid = threadIdx.x, wv = tid >> 6, lane = tid & 63;
  const int lr = lane & 15, lg = lane >> 4;

  // ---- stage K rows [t][d] (chunk-swizzled) and V^T rows [d][t] (swizzled), 512 threads ----
  {
    const unsigned short* ksrc = kb + ((size_t)b * 512) * 256 + h * 32;
    #pragma unroll
    for (int it = 0; it < 4; ++it) {
      int idx = tid + it * 512;
      int row = idx >> 2, g = idx & 3;
      int gs = g ^ ((row >> 1) & 3);
      *reinterpret_cast<int4*>(&Ks[row * 32 + gs * 8]) =
        *reinterpret_cast<const int4*>(&ksrc[(size_t)row * 256 + g * 8]);
    }
    const unsigned short* vsrc = vT + ((size_t)(b * 8 + h) * 32) * 512;
    #pragma unroll
    for (int it = 0; it < 4; ++it) {
      int idx = tid + it * 512;
      int d = idx >> 6, cg = idx & 63;
      int col = (cg * 8) ^ ((d & 7) << 3);
      *reinterpret_cast<int4*>(&Vs[d * 512 + col]) =
        *reinterpret_cast<const int4*>(&vsrc[(size_t)d * 512 + cg * 8]);
    }
  }
  __syncthreads();

  const float slope2 = exp2f(-(float)(h + 1)) * LOG2E; // ALiBi slope, log2 domain
  float cc[16];
  #pragma unroll
  for (int t = 0; t < 4; ++t)
    #pragma unroll
    for (int r = 0; r < 4; ++r) cc[t * 4 + r] = slope2 * (float)(t * 16 + r);
  const int swz = (lr & 7) << 4;
  const int kchunk = (lg ^ ((lr >> 1) & 3)) * 8;       // Ks swizzled chunk position
  char* Pw = Pb + wv * 4096;

  const int g = wv;                                    // global wave id 0..7
  const int c0 = g, c1 = 15 - g, c2 = 16 + g, c3 = 31 - g;
  CSt s0, s1, s2, s3;
  attn_init(s0, c0, qb, b, h, lr, lg, slope2);
  attn_init(s1, c1, qb, b, h, lr, lg, slope2);
  attn_init(s2, c2, qb, b, h, lr, lg, slope2);
  attn_init(s3, c3, qb, b, h, lr, lg, slope2);
  const int n0 = c0 / 4 + 1, n1 = c1 / 4 + 1, n2 = c2 / 4 + 1, n3 = c3 / 4 + 1;

  for (int s = 0; s < n3; s += 2) {
    const int kb0 = s * 64;
    bf16x8 kf[8], vf[8];                               // tiles s and s+1 (rows always < 512)
    #pragma unroll
    for (int t = 0; t < 8; ++t)
      kf[t] = *reinterpret_cast<const bf16x8*>(&Ks[(kb0 + t * 16 + lr) * 32 + kchunk]);
    #pragma unroll
    for (int ks = 0; ks < 4; ++ks)
      #pragma unroll
      for (int dt = 0; dt < 2; ++dt) {
        int d = dt * 16 + lr;
        int col = (kb0 + ks * 32 + lg * 8) ^ ((d & 7) << 3);
        vf[ks * 2 + dt] = *reinterpret_cast<const bf16x8*>(&Vs[d * 512 + col]);
      }
    chunk_phase(s0, s, n0, kf, vf, Pw, lr, lg, slope2, cc, swz);
    chunk_phase(s1, s, n1, kf, vf, Pw, lr, lg, slope2, cc, swz);
    chunk_phase(s2, s, n2, kf, vf, Pw, lr, lg, slope2, cc, swz);
    chunk_phase(s3, s, n3, kf, vf, Pw, lr, lg, slope2, cc, swz);
  }

  attn_fin(s0, ob, b, h, lr, lg);
  attn_fin(s1, ob, b, h, lr, lg);
  attn_fin(s2, ob, b, h, lr, lg);
  attn_fin(s3, ob, b, h, lr, lg);
}

extern "C" void kernel_launch(void* const* d_in, const int* in_sizes, int n_in,
                              void* d_out, int out_size, void* d_ws, size_t ws_size,
                              hipStream_t stream) {
  const float* x  = (const float*)d_in[0];
  const float* Wq = (const float*)d_in[1];
  const float* Wk = (const float*)d_in[2];
  const float* Wv = (const float*)d_in[3];
  const float* Wo = (const float*)d_in[4];
  const float* bo = (const float*)d_in[5];
  float* out = (float*)d_out;

  char* ws = (char*)d_ws;
  unsigned short* qb = (unsigned short*)(ws);                    // 8 MB
  unsigned short* kb = (unsigned short*)(ws + (8u  << 20));      // 8 MB
  unsigned short* vT = (unsigned short*)(ws + (16u << 20));      // 8 MB
  unsigned short* ob = (unsigned short*)(ws + (24u << 20));      // 8 MB
  unsigned short* wt = (unsigned short*)(ws + (32u << 20));      // 4 x 128 KB transposed weights

  WPtrs p;
  p.src[0] = Wq; p.src[1] = Wk; p.src[2] = Wv; p.src[3] = Wo;
  p.dst[0] = wt; p.dst[1] = wt + 65536; p.dst[2] = wt + 2 * 65536; p.dst[3] = wt + 3 * 65536;
  transpose_w<<<dim3(8, 8, 4), dim3(32, 8), 0, stream>>>(p);

  gemm_qkv<<<dim3(256, 3), 256, 0, stream>>>(x, wt, qb, kb, vT);
  attn_k<<<dim3(8, 32), 512, 0, stream>>>(qb, kb, vT, ob);
  gemm_out<<<dim3(128, 2), 256, 0, stream>>>(ob, wt + 3 * 65536, bo, out);
}

// Round 19
// 53.579 us; speedup vs baseline: 1.1965x; 1.0033x over previous
//
#include <hip/hip_runtime.h>
#include <stdint.h>

#define LOG2E 1.4426950408889634f
#define QSCALE_LN2 0.25506068f   // (1/sqrt(32)) * log2(e), folded into Q at projection

typedef __attribute__((ext_vector_type(8))) short bf16x8;
typedef __attribute__((ext_vector_type(4))) float f32x4;

__device__ __forceinline__ unsigned short f2bf(float f) {
  union { float f; unsigned int u; } v; v.f = f;
  unsigned int u = v.u;
  u += 0x7FFFu + ((u >> 16) & 1u);   // round-to-nearest-even
  return (unsigned short)(u >> 16);
}

__device__ __forceinline__ unsigned int cvt_pk_bf16(float lo, float hi) {
  unsigned int r;
  asm("v_cvt_pk_bf16_f32 %0, %1, %2" : "=v"(r) : "v"(lo), "v"(hi));
  return r;
}

// ---------- kernel: transpose 256x256 f32 -> bf16 (weights, k-fast for B-frags) ----------
struct WPtrs { const float* src[4]; unsigned short* dst[4]; };
__global__ void transpose_w(WPtrs p) {
  __shared__ float tile[32][33];
  const float* src = p.src[blockIdx.z];
  unsigned short* dst = p.dst[blockIdx.z];
  int x = blockIdx.x * 32 + threadIdx.x;
  int y = blockIdx.y * 32 + threadIdx.y;
  #pragma unroll
  for (int j = 0; j < 32; j += 8)
    tile[threadIdx.y + j][threadIdx.x] = src[(y + j) * 256 + x];
  __syncthreads();
  int xo = blockIdx.y * 32 + threadIdx.x;
  int yo = blockIdx.x * 32 + threadIdx.y;
  #pragma unroll
  for (int j = 0; j < 32; j += 8)
    dst[(yo + j) * 256 + xo] = f2bf(tile[threadIdx.x][threadIdx.y + j]);
}

// ---------- QKV GEMM (R5-proven): [16384,256] x [256,256], single pass over n ----------
// Q output is pre-scaled by QSCALE_LN2 (softmax scale folded, log2 domain).
__launch_bounds__(256, 3)
__global__ void gemm_qkv(const float* __restrict__ Ax,
                         const unsigned short* __restrict__ Wt,   // [n][k] transposed
                         unsigned short* __restrict__ q_out,
                         unsigned short* __restrict__ k_out,
                         unsigned short* __restrict__ vT) {
  __shared__ unsigned short As[64][72];    // 9 KB
  __shared__ unsigned short Bs[256][72];   // 36 KB
  const int tid = threadIdx.x;
  const int m0 = blockIdx.x * 64;
  const int wsel = blockIdx.y;
  const unsigned short* W = Wt + wsel * 65536;
  const int w = tid >> 6, lane = tid & 63;
  const int n0 = w * 64;
  const int lr = lane & 15, lg = lane >> 4;

  f32x4 acc[4][4] = {};

  for (int kt = 0; kt < 4; ++kt) {
    #pragma unroll
    for (int i = 0; i < 2; ++i) {          // A: 64 rows, f32 -> bf16 during staging
      int c = tid + i * 256;
      int row = c >> 3, colg = c & 7;
      const float* s = &Ax[(size_t)(m0 + row) * 256 + kt * 64 + colg * 8];
      float4 f0 = *reinterpret_cast<const float4*>(s);
      float4 f1 = *reinterpret_cast<const float4*>(s + 4);
      uint4 pk;
      pk.x = cvt_pk_bf16(f0.x, f0.y); pk.y = cvt_pk_bf16(f0.z, f0.w);
      pk.z = cvt_pk_bf16(f1.x, f1.y); pk.w = cvt_pk_bf16(f1.z, f1.w);
      *reinterpret_cast<uint4*>(&As[row][colg * 8]) = pk;
    }
    #pragma unroll
    for (int i = 0; i < 8; ++i) {          // B: 256 rows (full n)
      int c = tid + i * 256;
      int row = c >> 3, colg = c & 7;
      *reinterpret_cast<int4*>(&Bs[row][colg * 8]) =
        *reinterpret_cast<const int4*>(&W[(size_t)row * 256 + kt * 64 + colg * 8]);
    }
    __syncthreads();
    #pragma unroll
    for (int kk = 0; kk < 2; ++kk) {
      bf16x8 af[4], bfr[4];
      #pragma unroll
      for (int mf = 0; mf < 4; ++mf)
        af[mf] = *reinterpret_cast<const bf16x8*>(&As[mf * 16 + lr][kk * 32 + lg * 8]);
      #pragma unroll
      for (int nf = 0; nf < 4; ++nf)
        bfr[nf] = *reinterpret_cast<const bf16x8*>(&Bs[n0 + nf * 16 + lr][kk * 32 + lg * 8]);
      #pragma unroll
      for (int mf = 0; mf < 4; ++mf)
        #pragma unroll
        for (int nf = 0; nf < 4; ++nf)
          acc[mf][nf] = __builtin_amdgcn_mfma_f32_16x16x32_bf16(af[mf], bfr[nf], acc[mf][nf], 0, 0, 0);
    }
    __syncthreads();
  }

  if (wsel < 2) {
    unsigned short* dst = (wsel == 0) ? q_out : k_out;
    const float qs = (wsel == 0) ? QSCALE_LN2 : 1.0f;
    #pragma unroll
    for (int mf = 0; mf < 4; ++mf)
      #pragma unroll
      for (int nf = 0; nf < 4; ++nf)
        #pragma unroll
        for (int r = 0; r < 4; ++r)
          dst[(size_t)(m0 + mf * 16 + lg * 4 + r) * 256 + (n0 + nf * 16 + lr)] =
            f2bf(acc[mf][nf][r] * qs);
  } else {
    #pragma unroll
    for (int mf = 0; mf < 4; ++mf)
      #pragma unroll
      for (int nf = 0; nf < 4; ++nf) {
        int ncol = n0 + nf * 16 + lr;
        int h = ncol >> 5, d = ncol & 31;
        int m = m0 + mf * 16 + lg * 4;
        int b = m >> 9, t = m & 511;
        ushort4 pk;
        pk.x = f2bf(acc[mf][nf][0]); pk.y = f2bf(acc[mf][nf][1]);
        pk.z = f2bf(acc[mf][nf][2]); pk.w = f2bf(acc[mf][nf][3]);
        *reinterpret_cast<ushort4*>(&vT[((size_t)((b * 8 + h) * 32 + d)) * 512 + t]) = pk;
      }
  }
}

// ---------- output GEMM: [16384,256] x [256,128-tile] (proven shape) ----------
__launch_bounds__(256, 3)
__global__ void gemm_out(const unsigned short* __restrict__ Ab,
                         const unsigned short* __restrict__ W,    // wo^T [n][k]
                         const float* __restrict__ bo,
                         float* __restrict__ f_out) {
  __shared__ unsigned short As[128][72];
  __shared__ unsigned short Bs[128][72];
  const int tid = threadIdx.x;
  const int m0 = blockIdx.x * 128;
  const int n0 = blockIdx.y * 128;
  const int w = tid >> 6, lane = tid & 63;
  const int wm = (w >> 1) * 64, wn = (w & 1) * 64;
  const int lr = lane & 15, lg = lane >> 4;

  f32x4 acc[4][4] = {};

  for (int kt = 0; kt < 4; ++kt) {
    #pragma unroll
    for (int cc = 0; cc < 4; ++cc) {
      int c = tid + cc * 256;
      int row = c >> 3, colg = c & 7;
      *reinterpret_cast<int4*>(&As[row][colg * 8]) =
        *reinterpret_cast<const int4*>(&Ab[(size_t)(m0 + row) * 256 + kt * 64 + colg * 8]);
      *reinterpret_cast<int4*>(&Bs[row][colg * 8]) =
        *reinterpret_cast<const int4*>(&W[(size_t)(n0 + row) * 256 + kt * 64 + colg * 8]);
    }
    __syncthreads();
    #pragma unroll
    for (int kk = 0; kk < 2; ++kk) {
      bf16x8 af[4], bfr[4];
      #pragma unroll
      for (int mf = 0; mf < 4; ++mf)
        af[mf] = *reinterpret_cast<const bf16x8*>(&As[wm + mf * 16 + lr][kk * 32 + lg * 8]);
      #pragma unroll
      for (int nf = 0; nf < 4; ++nf)
        bfr[nf] = *reinterpret_cast<const bf16x8*>(&Bs[wn + nf * 16 + lr][kk * 32 + lg * 8]);
      #pragma unroll
      for (int mf = 0; mf < 4; ++mf)
        #pragma unroll
        for (int nf = 0; nf < 4; ++nf)
          acc[mf][nf] = __builtin_amdgcn_mfma_f32_16x16x32_bf16(af[mf], bfr[nf], acc[mf][nf], 0, 0, 0);
    }
    __syncthreads();
  }

  #pragma unroll
  for (int mf = 0; mf < 4; ++mf)
    #pragma unroll
    for (int nf = 0; nf < 4; ++nf)
      #pragma unroll
      for (int r = 0; r < 4; ++r) {
        int ncol = n0 + wn + nf * 16 + lr;
        f_out[(size_t)(m0 + wm + mf * 16 + lg * 4 + r) * 256 + ncol] = acc[mf][nf][r] + bo[ncol];
      }
}

// ---------- fused causal attention with ALiBi: ONE block per (b,h), 8 waves ----------
// grid (8, 32) = 256 blocks, 512 threads, 96 KB static LDS (1 block/CU).
// K/V staged ONCE per (b,h). Wave g = wv in 0..7 runs the R12 chunk set
// {g, 15-g, 16+g, 31-g} with byte-identical step code.
struct CSt {
  bf16x8 qf;
  f32x4 o0, o1;
  float m, l, bb0;
  int nfull, qq;
};

__device__ __forceinline__ void attn_init(CSt& st, int c, const unsigned short* qb,
    int b, int h, int lr, int lg, float slope2) {
  st.qq = c * 16;
  st.qf = *reinterpret_cast<const bf16x8*>(
      &qb[(size_t)(b * 512 + st.qq + lr) * 256 + h * 32 + lg * 8]);
  f32x4 z = {0.f, 0.f, 0.f, 0.f};
  st.o0 = z; st.o1 = z;
  st.m = -1e30f; st.l = 0.f;
  st.nfull = (st.qq >= 63) ? ((st.qq - 63) / 64 + 1) : 0;
  st.bb0 = slope2 * (float)(lg * 4 - lr - st.qq);
}

// single-step (R12-proven)
__device__ __forceinline__ void attn_step(CSt& st, int s,
    const bf16x8* kf, const bf16x8* vf, char* __restrict__ Pw,
    int lr, int lg, float slope2, const float* cc, int swz) {
  const int kb0 = s * 64;
  f32x4 sv[4];
  __builtin_amdgcn_s_setprio(1);
  #pragma unroll
  for (int t = 0; t < 4; ++t) {
    f32x4 z = {0.f, 0.f, 0.f, 0.f};
    sv[t] = __builtin_amdgcn_mfma_f32_16x16x32_bf16(kf[t], st.qf, z, 0, 0, 0);
  }
  __builtin_amdgcn_s_setprio(0);
  float bb = st.bb0 + slope2 * (float)kb0;
  float x[16];
  #pragma unroll
  for (int t = 0; t < 4; ++t)
    #pragma unroll
    for (int r = 0; r < 4; ++r)
      x[t * 4 + r] = sv[t][r] + (bb + cc[t * 4 + r]);
  if (s >= st.nfull) {                                // boundary step: causal mask
    int thr = st.qq + lr - kb0 - lg * 4;
    #pragma unroll
    for (int t = 0; t < 4; ++t)
      #pragma unroll
      for (int r = 0; r < 4; ++r)
        x[t * 4 + r] = ((t * 16 + r) <= thr) ? x[t * 4 + r] : -1e30f;
  }
  float bm = x[0];
  #pragma unroll
  for (int j = 1; j < 16; ++j) bm = fmaxf(bm, x[j]);
  bm = fmaxf(bm, __shfl_xor(bm, 16));
  bm = fmaxf(bm, __shfl_xor(bm, 32));
  float mn = fmaxf(st.m, bm);
  float alpha = __builtin_amdgcn_exp2f(st.m - mn);
  st.m = mn;
  st.l *= alpha;
  #pragma unroll
  for (int r = 0; r < 4; ++r) { st.o0[r] *= alpha; st.o1[r] *= alpha; }
  float ps = 0.f;
  #pragma unroll
  for (int j = 0; j < 16; ++j) { x[j] = __builtin_amdgcn_exp2f(x[j] - mn); ps += x[j]; }
  st.l += ps;
  char* Prow = Pw + lr * 256;                          // 256 B rows; use first 128 B
  #pragma unroll
  for (int t = 0; t < 4; ++t)
    #pragma unroll
    for (int pp = 0; pp < 2; ++pp) {
      unsigned int w2 = cvt_pk_bf16(x[t * 4 + 2 * pp], x[t * 4 + 2 * pp + 1]);
      *reinterpret_cast<unsigned int*>(Prow + ((t * 32 + lg * 8 + pp * 4) ^ swz)) = w2;
    }
  __builtin_amdgcn_s_setprio(1);
  #pragma unroll
  for (int ks = 0; ks < 2; ++ks) {
    bf16x8 pb = *reinterpret_cast<const bf16x8*>(Prow + ((ks * 64 + lg * 16) ^ swz));
    st.o0 = __builtin_amdgcn_mfma_f32_16x16x32_bf16(vf[ks * 2 + 0], pb, st.o0, 0, 0, 0);
    st.o1 = __builtin_amdgcn_mfma_f32_16x16x32_bf16(vf[ks * 2 + 1], pb, st.o1, 0, 0, 0);
  }
  __builtin_amdgcn_s_setprio(0);
}

// double-step: tiles s and s+1 (128 keys), one online-softmax update.
__device__ __forceinline__ void attn_step2(CSt& st, int s, bool maskB,
    const bf16x8* kf, const bf16x8* vf, char* __restrict__ Pw,
    int lr, int lg, float slope2, const float* cc, int swz) {
  const int kb0 = s * 64;
  f32x4 sv[8];
  __builtin_amdgcn_s_setprio(1);
  #pragma unroll
  for (int t = 0; t < 8; ++t) {
    f32x4 z = {0.f, 0.f, 0.f, 0.f};
    sv[t] = __builtin_amdgcn_mfma_f32_16x16x32_bf16(kf[t], st.qf, z, 0, 0, 0);
  }
  __builtin_amdgcn_s_setprio(0);
  const float bbA = st.bb0 + slope2 * (float)kb0;
  const float bbB = bbA + slope2 * 64.0f;
  float x[32];
  #pragma unroll
  for (int t = 0; t < 4; ++t)
    #pragma unroll
    for (int r = 0; r < 4; ++r) {
      x[t * 4 + r]      = sv[t][r]     + (bbA + cc[t * 4 + r]);
      x[16 + t * 4 + r] = sv[4 + t][r] + (bbB + cc[t * 4 + r]);
    }
  if (maskB) {
    int thr = st.qq + lr - (kb0 + 64) - lg * 4;
    #pragma unroll
    for (int t = 0; t < 4; ++t)
      #pragma unroll
      for (int r = 0; r < 4; ++r)
        x[16 + t * 4 + r] = ((t * 16 + r) <= thr) ? x[16 + t * 4 + r] : -1e30f;
  }
  float bm = x[0];
  #pragma unroll
  for (int j = 1; j < 32; ++j) bm = fmaxf(bm, x[j]);
  bm = fmaxf(bm, __shfl_xor(bm, 16));
  bm = fmaxf(bm, __shfl_xor(bm, 32));
  float mn = fmaxf(st.m, bm);
  float alpha = __builtin_amdgcn_exp2f(st.m - mn);
  st.m = mn;
  st.l *= alpha;
  #pragma unroll
  for (int r = 0; r < 4; ++r) { st.o0[r] *= alpha; st.o1[r] *= alpha; }
  float ps = 0.f;
  #pragma unroll
  for (int j = 0; j < 32; ++j) { x[j] = __builtin_amdgcn_exp2f(x[j] - mn); ps += x[j]; }
  st.l += ps;
  char* Prow = Pw + lr * 256;                          // [0,128): tile A, [128,256): tile B
  #pragma unroll
  for (int t = 0; t < 4; ++t)
    #pragma unroll
    for (int pp = 0; pp < 2; ++pp) {
      const int cb = (t * 32 + lg * 8 + pp * 4) ^ swz;
      *reinterpret_cast<unsigned int*>(Prow + cb) =
          cvt_pk_bf16(x[t * 4 + 2 * pp], x[t * 4 + 2 * pp + 1]);
      *reinterpret_cast<unsigned int*>(Prow + 128 + cb) =
          cvt_pk_bf16(x[16 + t * 4 + 2 * pp], x[16 + t * 4 + 2 * pp + 1]);
    }
  __builtin_amdgcn_s_setprio(1);
  #pragma unroll
  for (int ks = 0; ks < 4; ++ks) {
    const int cb = (ks >> 1) * 128 + ((((ks & 1) * 64) + lg * 16) ^ swz);
    bf16x8 pb = *reinterpret_cast<const bf16x8*>(Prow + cb);
    st.o0 = __builtin_amdgcn_mfma_f32_16x16x32_bf16(vf[ks * 2 + 0], pb, st.o0, 0, 0, 0);
    st.o1 = __builtin_amdgcn_mfma_f32_16x16x32_bf16(vf[ks * 2 + 1], pb, st.o1, 0, 0, 0);
  }
  __builtin_amdgcn_s_setprio(0);
}

__device__ __forceinline__ void attn_fin(CSt& st, unsigned short* __restrict__ ob,
                                         int b, int h, int lr, int lg) {
  float l = st.l;
  l += __shfl_xor(l, 16);
  l += __shfl_xor(l, 32);
  float inv = 1.0f / l;
  unsigned int w0 = cvt_pk_bf16(st.o0[0] * inv, st.o0[1] * inv);
  unsigned int w1 = cvt_pk_bf16(st.o0[2] * inv, st.o0[3] * inv);
  unsigned int w2 = cvt_pk_bf16(st.o1[0] * inv, st.o1[1] * inv);
  unsigned int w3 = cvt_pk_bf16(st.o1[2] * inv, st.o1[3] * inv);
  size_t obase = (size_t)(b * 512 + st.qq + lr) * 256 + h * 32;
  *reinterpret_cast<uint2*>(&ob[obase + lg * 4]) = make_uint2(w0, w1);
  *reinterpret_cast<uint2*>(&ob[obase + 16 + lg * 4]) = make_uint2(w2, w3);
}

// dispatch one chunk's work for the tile-pair starting at s
__device__ __forceinline__ void chunk_phase(CSt& st, int s, int nc,
    const bf16x8* kf, const bf16x8* vf, char* Pw,
    int lr, int lg, float slope2, const float* cc, int swz) {
  if (s >= nc) return;
  if (s + 1 < nc)
    attn_step2(st, s, (s + 2 >= nc), kf, vf, Pw, lr, lg, slope2, cc, swz);
  else
    attn_step(st, s, kf, vf, Pw, lr, lg, slope2, cc, swz);   // odd tail, self-masks
}

__launch_bounds__(512)
__global__ void attn_k(const unsigned short* __restrict__ qb,
                       const unsigned short* __restrict__ kb,
                       const unsigned short* __restrict__ vT,
                       unsigned short* __restrict__ ob) {
  __shared__ unsigned short Ks[512 * 32];   // chunk-swizzled, 32 KB
  __shared__ unsigned short Vs[32 * 512];   // col-swizzled, 32 KB
  __shared__ char Pb[32768];                // 8 waves x 4 KB strips
  const int h = blockIdx.x, b = blockIdx.y;
  const int tid = threadIdx.x, wv = tid >> 6, lane = tid & 63;
  const int lr = lane & 15, lg = lane >> 4;

  // ---- stage K rows [t][d] (chunk-swizzled) and V^T rows [d][t] (swizzled), 512 threads ----
  {
    const unsigned short* ksrc = kb + ((size_t)b * 512) * 256 + h * 32;
    #pragma unroll
    for (int it = 0; it < 4; ++it) {
      int idx = tid + it * 512;
      int row = idx >> 2, g = idx & 3;
      int gs = g ^ ((row >> 1) & 3);
      *reinterpret_cast<int4*>(&Ks[row * 32 + gs * 8]) =
        *reinterpret_cast<const int4*>(&ksrc[(size_t)row * 256 + g * 8]);
    }
    const unsigned short* vsrc = vT + ((size_t)(b * 8 + h) * 32) * 512;
    #pragma unroll
    for (int it = 0; it < 4; ++it) {
      int idx = tid + it * 512;
      int d = idx >> 6, cg = idx & 63;
      int col = (cg * 8) ^ ((d & 7) << 3);
      *reinterpret_cast<int4*>(&Vs[d * 512 + col]) =
        *reinterpret_cast<const int4*>(&vsrc[(size_t)d * 512 + cg * 8]);
    }
  }
  __syncthreads();

  const float slope2 = exp2f(-(float)(h + 1)) * LOG2E; // ALiBi slope, log2 domain
  float cc[16];
  #pragma unroll
  for (int t = 0; t < 4; ++t)
    #pragma unroll
    for (int r = 0; r < 4; ++r) cc[t * 4 + r] = slope2 * (float)(t * 16 + r);
  const int swz = (lr & 7) << 4;
  const int kchunk = (lg ^ ((lr >> 1) & 3)) * 8;       // Ks swizzled chunk position
  char* Pw = Pb + wv * 4096;

  const int g = wv;                                    // global wave id 0..7
  const int c0 = g, c1 = 15 - g, c2 = 16 + g, c3 = 31 - g;
  CSt s0, s1, s2, s3;
  attn_init(s0, c0, qb, b, h, lr, lg, slope2);
  attn_init(s1, c1, qb, b, h, lr, lg, slope2);
  attn_init(s2, c2, qb, b, h, lr, lg, slope2);
  attn_init(s3, c3, qb, b, h, lr, lg, slope2);
  const int n0 = c0 / 4 + 1, n1 = c1 / 4 + 1, n2 = c2 / 4 + 1, n3 = c3 / 4 + 1;

  for (int s = 0; s < n3; s += 2) {
    const int kb0 = s * 64;
    bf16x8 kf[8], vf[8];                               // tiles s and s+1 (rows always < 512)
    #pragma unroll
    for (int t = 0; t < 8; ++t)
      kf[t] = *reinterpret_cast<const bf16x8*>(&Ks[(kb0 + t * 16 + lr) * 32 + kchunk]);
    #pragma unroll
    for (int ks = 0; ks < 4; ++ks)
      #pragma unroll
      for (int dt = 0; dt < 2; ++dt) {
        int d = dt * 16 + lr;
        int col = (kb0 + ks * 32 + lg * 8) ^ ((d & 7) << 3);
        vf[ks * 2 + dt] = *reinterpret_cast<const bf16x8*>(&Vs[d * 512 + col]);
      }
    chunk_phase(s0, s, n0, kf, vf, Pw, lr, lg, slope2, cc, swz);
    chunk_phase(s1, s, n1, kf, vf, Pw, lr, lg, slope2, cc, swz);
    chunk_phase(s2, s, n2, kf, vf, Pw, lr, lg, slope2, cc, swz);
    chunk_phase(s3, s, n3, kf, vf, Pw, lr, lg, slope2, cc, swz);
  }

  attn_fin(s0, ob, b, h, lr, lg);
  attn_fin(s1, ob, b, h, lr, lg);
  attn_fin(s2, ob, b, h, lr, lg);
  attn_fin(s3, ob, b, h, lr, lg);
}

extern "C" void kernel_launch(void* const* d_in, const int* in_sizes, int n_in,
                              void* d_out, int out_size, void* d_ws, size_t ws_size,
                              hipStream_t stream) {
  const float* x  = (const float*)d_in[0];
  const float* Wq = (const float*)d_in[1];
  const float* Wk = (const float*)d_in[2];
  const float* Wv = (const float*)d_in[3];
  const float* Wo = (const float*)d_in[4];
  const float* bo = (const float*)d_in[5];
  float* out = (float*)d_out;

  char* ws = (char*)d_ws;
  unsigned short* qb = (unsigned short*)(ws);                    // 8 MB
  unsigned short* kb = (unsigned short*)(ws + (8u  << 20));      // 8 MB
  unsigned short* vT = (unsigned short*)(ws + (16u << 20));      // 8 MB
  unsigned short* ob = (unsigned short*)(ws + (24u << 20));      // 8 MB
  unsigned short* wt = (unsigned short*)(ws + (32u << 20));      // 4 x 128 KB transposed weights

  WPtrs p;
  p.src[0] = Wq; p.src[1] = Wk; p.src[2] = Wv; p.src[3] = Wo;
  p.dst[0] = wt; p.dst[1] = wt + 65536; p.dst[2] = wt + 2 * 65536; p.dst[3] = wt + 3 * 65536;
  transpose_w<<<dim3(8, 8, 4), dim3(32, 8), 0, stream>>>(p);

  gemm_qkv<<<dim3(256, 3), 256, 0, stream>>>(x, wt, qb, kb, vT);
  attn_k<<<dim3(8, 32), 512, 0, stream>>>(qb, kb, vT, ob);
  gemm_out<<<dim3(128, 2), 256, 0, stream>>>(ob, wt + 3 * 65536, bo, out);
}